// Round 10
// baseline (148.667 us; speedup 1.0000x reference)
//
#include <hip/hip_runtime.h>
#include <hip/hip_bf16.h>

typedef __attribute__((ext_vector_type(8))) short short8;
typedef __attribute__((ext_vector_type(4))) float f32x4;

#define DEVI __device__ __forceinline__

DEVI unsigned short f2bf(float f) {
    union { float f; unsigned u; } v; v.f = f;
    unsigned r = v.u + 0x7FFFu + ((v.u >> 16) & 1u);   // RNE
    return (unsigned short)(r >> 16);
}

// packed f32x2 -> bf16x2 (v_cvt_pk_bf16_f32), RNE
DEVI unsigned cvtpk_bf16(float lo, float hi) {
    float2 t; t.x = lo; t.y = hi;
    __hip_bfloat162 h = __float22bfloat162_rn(t);
    union { __hip_bfloat162 h; unsigned u; } c; c.h = h;
    return c.u;
}

// direct HBM->LDS DMA, 16B per lane. lds dest = wave-uniform base + lane*16.
DEVI void gload_lds16(const void* g, void* l) {
    __builtin_amdgcn_global_load_lds(
        (const __attribute__((address_space(1))) unsigned int*)(unsigned long long)g,
        (__attribute__((address_space(3))) unsigned int*)(unsigned int)(unsigned long long)l,
        16, 0, 0);
}

// ---------------- 4-qubit circuit, one sample per thread ----------------
DEVI void run_circuit(const float lat[4], const float* __restrict__ qw, float out4[4])
{
    float cw[4], sw[4];
#pragma unroll
    for (int w = 0; w < 4; ++w) sincosf(0.5f * lat[w], &sw[w], &cw[w]);

    float sr[16], si[16];
#pragma unroll
    for (int s = 0; s < 16; ++s) {
        float mag = 1.f; int p = 0;
#pragma unroll
        for (int w = 0; w < 4; ++w) {
            int b = (s >> (3 - w)) & 1;
            mag *= b ? sw[w] : cw[w];
            p += b;
        }
        p &= 3;
        sr[s] = (p == 0) ? mag : ((p == 2) ? -mag : 0.f);
        si[s] = (p == 1) ? -mag : ((p == 3) ? mag : 0.f);
    }

#pragma unroll
    for (int L = 0; L < 3; ++L) {
#pragma unroll
        for (int q = 0; q < 4; ++q) {
            const float* gq = qw + (L * 4 + q) * 3;
            float phi = gq[0], th = gq[1], om = gq[2];
            float ct, st;
            sincosf(0.5f * th, &st, &ct);
            float ap = 0.5f * (phi + om), am = 0.5f * (phi - om);
            float cap, sap, cam, sam;
            sincosf(ap, &sap, &cap);
            sincosf(am, &sam, &cam);
            float u00r =  ct * cap, u00i = -ct * sap;
            float u01r = -st * cam, u01i = -st * sam;
            float u10r =  st * cam, u10i = -st * sam;
            float u11r =  ct * cap, u11i =  ct * sap;
            int bm = 8 >> q;
#pragma unroll
            for (int i = 0; i < 16; ++i) {
                if (i & bm) continue;
                int j = i | bm;
                float ar = sr[i], ai = si[i], br = sr[j], bi = si[j];
                sr[i] = u00r*ar - u00i*ai + u01r*br - u01i*bi;
                si[i] = u00r*ai + u00i*ar + u01r*bi + u01i*br;
                sr[j] = u10r*ar - u10i*ai + u11r*br - u11i*bi;
                si[j] = u10r*ai + u10i*ar + u11r*bi + u11i*br;
            }
        }
#pragma unroll
        for (int q = 0; q < 3; ++q) {
            int cm = 8 >> q, tm = 8 >> (q + 1);
#pragma unroll
            for (int i = 0; i < 16; ++i) {
                if ((i & cm) && !(i & tm)) {
                    int j = i | tm;
                    float tr = sr[i]; sr[i] = sr[j]; sr[j] = tr;
                    float ti = si[i]; si[i] = si[j]; si[j] = ti;
                }
            }
        }
    }
#pragma unroll
    for (int q = 0; q < 4; ++q) {
        int bm = 8 >> q;
        float e = 0.f;
#pragma unroll
        for (int i = 0; i < 16; ++i) {
            float p = sr[i]*sr[i] + si[i]*si[i];
            e += (i & bm) ? -p : p;
        }
        out4[q] = e;
    }
}

// ---------------- prep: weights -> bf16 [N][K] in ws ----------------
// ushort elem offsets: w0eT=0 (128x2048), w1eT=262144 (64x128),
// w1dT=270336 (128x64), w2dT=278528 (2048x128).
__global__ void prep_kernel(const float* __restrict__ ew0, const float* __restrict__ ew1,
                            const float* __restrict__ dw1, const float* __restrict__ dw2,
                            unsigned short* __restrict__ wsb)
{
    int i = blockIdx.x * 256 + threadIdx.x;
    if (i < 262144) {
        int n = i >> 11, k = i & 2047;
        wsb[i] = f2bf(ew0[k * 128 + n]);
    } else if (i < 270336) {
        int t = i - 262144; int n = t >> 7, k = t & 127;
        wsb[i] = f2bf(ew1[k * 64 + n]);
    } else if (i < 278528) {
        int t = i - 270336; int n = t >> 6, k = t & 63;
        wsb[i] = f2bf(dw1[k * 128 + n]);
    } else if (i < 540672) {
        int t = i - 278528; int n = t >> 7, k = t & 127;
        wsb[i] = f2bf(dw2[k * 2048 + n]);
    }
}

// ================= fully-fused kernel: x -> out, BM=16, 1024 blocks =================
// LDS plan (40960 B -> 4 blocks/CU = 16 waves/CU):
//   P1:   A0@0(4K) A1@4096(4K) ([16][256B] swz f32) | B0@8192(16K) B1@24576(16K) ([128][128B])
//   tail: W1E@0 (16K, [64][256B])  W1D@16384 (16K, [128][128B])
//         H1@32768 (4K, [16][256B] swz bf16)  H2@36864 (4K, f32[16][64])
//   P3:   HD@0 (2K, [16][128B] swz)        [W1E dead]
//   P4:   GA@2048 (4K, [16][256B] swz)     [W1E dead]
//   P5:   W2a@8192(16K) W2b@24576(16K) ([64][256B] swz, 64-col chunks, dbuf)
__launch_bounds__(256, 4)
__global__ void fused_kernel(const float* __restrict__ x,
                             const unsigned short* __restrict__ w0T,
                             const float* __restrict__ b0e,
                             const unsigned short* __restrict__ w1eT,
                             const float* __restrict__ b1e,
                             const float* __restrict__ w2e,
                             const float* __restrict__ b2e,
                             const float* __restrict__ qw,
                             const float* __restrict__ w0d,
                             const float* __restrict__ b0d,
                             const unsigned short* __restrict__ w1dT,
                             const float* __restrict__ b1d,
                             const unsigned short* __restrict__ w2T,
                             const float* __restrict__ b2d,
                             float* __restrict__ out)
{
    __shared__ __align__(16) char smem[40960];
    char* const W1E = smem;                     // 16K (tail->P2)
    char* const W1D = smem + 16384;             // 16K (tail->P4)
    char* const H1  = smem + 32768;             // 4K  (P1 epi -> P2)
    float* const H2 = (float*)(smem + 36864);   // 4K  (P2 -> P3)
    char* const HD  = smem;                     // 2K  (P3 -> P4, over dead W1E)
    char* const GA  = smem + 2048;              // 4K  (P4 -> P5, over dead W1E)

    const int tid = threadIdx.x;
    const int lane = tid & 63;
    const int wv = tid >> 6;
    const int l16 = lane & 15, lq = lane >> 4;
    const int m0 = blockIdx.x * 16;

    // ======== phase 1: GEMM1  h1 = relu(x @ enc_w0 + b0e), 16x128, K=2048 ========
    {
        // A: 1 instr/wave (4 rows x 256B); B: 4 instr/wave (8 rows x 128B each)
        const int rA = wv * 4 + (lane >> 4);
        const char* sA = (const char*)(x + (long)(m0 + rA) * 2048 + ((lane & 15) ^ (rA & 7)) * 4);
        const int rB0 = wv * 32 +  0 + (lane >> 3);
        const int rB1 = wv * 32 +  8 + (lane >> 3);
        const int rB2 = wv * 32 + 16 + (lane >> 3);
        const int rB3 = wv * 32 + 24 + (lane >> 3);
        const char* sB0 = (const char*)(w0T + rB0 * 2048 + ((lane & 7) ^ (rB0 & 7)) * 8);
        const char* sB1 = (const char*)(w0T + rB1 * 2048 + ((lane & 7) ^ (rB1 & 7)) * 8);
        const char* sB2 = (const char*)(w0T + rB2 * 2048 + ((lane & 7) ^ (rB2 & 7)) * 8);
        const char* sB3 = (const char*)(w0T + rB3 * 2048 + ((lane & 7) ^ (rB3 & 7)) * 8);
        const int aoff  = wv * 1024;
        const int boff0 = wv * 4096;
        const int boff1 = wv * 4096 + 1024;
        const int boff2 = wv * 4096 + 2048;
        const int boff3 = wv * 4096 + 3072;

        auto issue = [&](int cur) {
            char* Ab = smem + (cur ? 4096 : 0);
            char* Bb = smem + (cur ? 24576 : 8192);
            gload_lds16(sA, Ab + aoff);   sA  += 256;
            gload_lds16(sB0, Bb + boff0); sB0 += 128;
            gload_lds16(sB1, Bb + boff1); sB1 += 128;
            gload_lds16(sB2, Bb + boff2); sB2 += 128;
            gload_lds16(sB3, Bb + boff3); sB3 += 128;
        };

        f32x4 acc[2];
#pragma unroll
        for (int b = 0; b < 2; ++b) acc[b] = (f32x4)(0.f);

        const int arow = l16;
        const int ah = arow & 7;

        issue(0);
        __syncthreads();

        for (int t = 0; t < 32; ++t) {
            if (t < 31) issue((t + 1) & 1);
            const char* Ab = smem + ((t & 1) ? 4096 : 0);
            const char* Bb = smem + ((t & 1) ? 24576 : 8192);
            const char* abase = Ab + arow * 256;
#pragma unroll
            for (int kk = 0; kk < 2; ++kk) {
                const int c = kk * 8 + lq * 2;
                float4 f0 = *(const float4*)(abase + ((c ^ ah) << 4));
                float4 f1 = *(const float4*)(abase + (((c + 1) ^ ah) << 4));
                union { unsigned u[4]; short8 s; } pk;
                pk.u[0] = cvtpk_bf16(f0.x, f0.y);
                pk.u[1] = cvtpk_bf16(f0.z, f0.w);
                pk.u[2] = cvtpk_bf16(f1.x, f1.y);
                pk.u[3] = cvtpk_bf16(f1.z, f1.w);
                short8 aF = pk.s;
#pragma unroll
                for (int fn = 0; fn < 2; ++fn) {
                    int n = wv * 32 + fn * 16 + l16;
                    short8 bF = *(const short8*)(Bb + n * 128 + (((kk * 4 + lq) ^ (n & 7)) << 4));
                    acc[fn] = __builtin_amdgcn_mfma_f32_16x16x32_bf16(aF, bF, acc[fn], 0, 0, 0);
                }
            }
            __syncthreads();
        }

        // ---- tail: stage W1E/W1D into dead P1 regions; epilogue -> H1 ----
        {
            const int r16 = wv * 16 + (lane >> 4);
            const int s16 = lane & 15;
            const int r8  = wv * 32 + (lane >> 3);
            const int s8  = lane & 7;
#pragma unroll
            for (int i = 0; i < 4; ++i) {
                int row = r16 + i * 4;
                gload_lds16(w1eT + row * 128 + ((s16 ^ (row & 7)) * 8),
                            W1E + wv * 4096 + i * 1024);
            }
#pragma unroll
            for (int i = 0; i < 4; ++i) {
                int row = r8 + i * 8;
                gload_lds16(w1dT + row * 64 + ((s8 ^ (row & 7)) * 8),
                            W1D + wv * 4096 + i * 1024);
            }
        }

        float b0v[2];
#pragma unroll
        for (int fn = 0; fn < 2; ++fn) b0v[fn] = b0e[wv * 32 + fn * 16 + l16];
#pragma unroll
        for (int fn = 0; fn < 2; ++fn)
#pragma unroll
            for (int r = 0; r < 4; ++r) {
                int row = lq * 4 + r;
                int col = wv * 32 + fn * 16 + l16;
                float v = fmaxf(acc[fn][r] + b0v[fn], 0.f);
                *(unsigned short*)(H1 + row * 256 + ((((col >> 3) ^ (row & 7)) << 4) | ((col & 7) << 1))) = f2bf(v);
            }
    }
    __syncthreads();

    // ======== phase 2: GEMM2e  h2 = relu(h1 @ enc_w1 + b1e), 16x64, K=128 ========
    {
        f32x4 acc2 = (f32x4)(0.f);
#pragma unroll
        for (int kk = 0; kk < 4; ++kk) {
            int row = l16;
            short8 aF = *(const short8*)(H1 + row * 256 + (((kk * 4 + lq) ^ (row & 7)) << 4));
            int n = wv * 16 + l16;
            short8 bF = *(const short8*)(W1E + n * 256 + (((kk * 4 + lq) ^ (n & 7)) << 4));
            acc2 = __builtin_amdgcn_mfma_f32_16x16x32_bf16(aF, bF, acc2, 0, 0, 0);
        }
        float b1v = b1e[wv * 16 + l16];
#pragma unroll
        for (int r = 0; r < 4; ++r) {
            int row = lq * 4 + r;
            int col = wv * 16 + l16;
            H2[row * 64 + col] = fmaxf(acc2[r] + b1v, 0.f);
        }
    }
    __syncthreads();

    // ======== phase 3: latent + circuit + dec layer0 (one row per thread) ========
    if (tid < 16) {
        float lat[4];
#pragma unroll
        for (int j = 0; j < 4; ++j) lat[j] = b2e[j];
        const float* h2row = H2 + tid * 64;
#pragma unroll 8
        for (int k = 0; k < 64; ++k) {
            float hv = h2row[k];
            float4 wv4 = *(const float4*)(w2e + k * 32);   // enc_w2 row k, cols 0..3
            lat[0] = fmaf(hv, wv4.x, lat[0]);
            lat[1] = fmaf(hv, wv4.y, lat[1]);
            lat[2] = fmaf(hv, wv4.z, lat[2]);
            lat[3] = fmaf(hv, wv4.w, lat[3]);
        }
        float o4[4];
        run_circuit(lat, qw, o4);
#pragma unroll
        for (int s = 0; s < 8; ++s) {
            uint4 pk;
            unsigned tmp[4];
#pragma unroll
            for (int p = 0; p < 4; ++p) {
                int c0 = s * 8 + p * 2;
                float v0 = fmaxf(o4[0]*w0d[c0]     + o4[1]*w0d[64+c0]   + o4[2]*w0d[128+c0]   + o4[3]*w0d[192+c0]   + b0d[c0],   0.f);
                float v1 = fmaxf(o4[0]*w0d[c0+1]   + o4[1]*w0d[64+c0+1] + o4[2]*w0d[128+c0+1] + o4[3]*w0d[192+c0+1] + b0d[c0+1], 0.f);
                tmp[p] = (unsigned)f2bf(v0) | ((unsigned)f2bf(v1) << 16);
            }
            pk.x = tmp[0]; pk.y = tmp[1]; pk.z = tmp[2]; pk.w = tmp[3];
            *(uint4*)(HD + tid * 128 + ((s ^ (tid & 7)) << 4)) = pk;
        }
    }
    __syncthreads();

    // ======== phase 4: GEMM2d  g = relu(hdec @ dec_w1 + b1d), 16x128, K=64 ========
    {
        f32x4 accg[2];
#pragma unroll
        for (int b = 0; b < 2; ++b) accg[b] = (f32x4)(0.f);
#pragma unroll
        for (int kk = 0; kk < 2; ++kk) {
            int row = l16;
            short8 aF = *(const short8*)(HD + row * 128 + (((kk * 4 + lq) ^ (row & 7)) << 4));
#pragma unroll
            for (int fn = 0; fn < 2; ++fn) {
                int n = wv * 32 + fn * 16 + l16;
                short8 bF = *(const short8*)(W1D + n * 128 + (((kk * 4 + lq) ^ (n & 7)) << 4));
                accg[fn] = __builtin_amdgcn_mfma_f32_16x16x32_bf16(aF, bF, accg[fn], 0, 0, 0);
            }
        }
        float b1v[2];
#pragma unroll
        for (int fn = 0; fn < 2; ++fn) b1v[fn] = b1d[wv * 32 + fn * 16 + l16];
#pragma unroll
        for (int fn = 0; fn < 2; ++fn)
#pragma unroll
            for (int r = 0; r < 4; ++r) {
                int row = lq * 4 + r;
                int col = wv * 32 + fn * 16 + l16;
                float v = fmaxf(accg[fn][r] + b1v[fn], 0.f);
                *(unsigned short*)(GA + row * 256 + ((((col >> 3) ^ (row & 7)) << 4) | ((col & 7) << 1))) = f2bf(v);
            }
    }
    __syncthreads();

    // ======== phase 5: GEMM3  out = g @ dec_w2 + b2d, 16x2048, K=128 ========
    // 32 chunks of 64 cols, dbuf W2a@8192 / W2b@24576 (over dead W1E/W1D/H1/H2).
    {
        auto w2issue = [&](int c) {
            char* W = smem + ((c & 1) ? 24576 : 8192);
            int base = c * 64;
#pragma unroll
            for (int i = 0; i < 4; ++i) {
                int row = wv * 16 + i * 4 + (lane >> 4);
                gload_lds16(w2T + (base + row) * 128 + (((lane & 15) ^ (row & 7)) * 8),
                            W + wv * 4096 + i * 1024);
            }
        };
        w2issue(0);
        __syncthreads();

        const int arow = l16;
        for (int c = 0; c < 32; ++c) {
            if (c < 31) w2issue(c + 1);
            const char* W = smem + ((c & 1) ? 24576 : 8192);
            f32x4 a3 = (f32x4)(0.f);
#pragma unroll
            for (int kk = 0; kk < 4; ++kk) {
                short8 aF = *(const short8*)(GA + arow * 256 + (((kk * 4 + lq) ^ (arow & 7)) << 4));
                int n = wv * 16 + l16;
                short8 bF = *(const short8*)(W + n * 256 + (((kk * 4 + lq) ^ (n & 7)) << 4));
                a3 = __builtin_amdgcn_mfma_f32_16x16x32_bf16(aF, bF, a3, 0, 0, 0);
            }
            int n0 = c * 64;
            float b2v = b2d[n0 + wv * 16 + l16];
#pragma unroll
            for (int r = 0; r < 4; ++r) {
                int row = m0 + lq * 4 + r;
                int col = n0 + wv * 16 + l16;
                out[(long)row * 2048 + col] = a3[r] + b2v;
            }
            __syncthreads();
        }
    }
}

extern "C" void kernel_launch(void* const* d_in, const int* in_sizes, int n_in,
                              void* d_out, int out_size, void* d_ws, size_t ws_size,
                              hipStream_t stream)
{
    (void)in_sizes; (void)n_in; (void)out_size; (void)ws_size;
    const float* x      = (const float*)d_in[0];
    const float* enc_w0 = (const float*)d_in[1];
    const float* enc_b0 = (const float*)d_in[2];
    const float* enc_w1 = (const float*)d_in[3];
    const float* enc_b1 = (const float*)d_in[4];
    const float* enc_w2 = (const float*)d_in[5];
    const float* enc_b2 = (const float*)d_in[6];
    const float* qw     = (const float*)d_in[7];
    const float* dec_w0 = (const float*)d_in[8];
    const float* dec_b0 = (const float*)d_in[9];
    const float* dec_w1 = (const float*)d_in[10];
    const float* dec_b1 = (const float*)d_in[11];
    const float* dec_w2 = (const float*)d_in[12];
    const float* dec_b2 = (const float*)d_in[13];

    unsigned short* wsb = (unsigned short*)d_ws;

    prep_kernel<<<2112, 256, 0, stream>>>(enc_w0, enc_w1, dec_w1, dec_w2, wsb);
    fused_kernel<<<1024, 256, 0, stream>>>(x, wsb, enc_b0,
                                           wsb + 262144, enc_b1, enc_w2, enc_b2, qw,
                                           dec_w0, dec_b0, wsb + 270336, dec_b1,
                                           wsb + 278528, dec_b2, (float*)d_out);
}

// Round 11
// 88.934 us; speedup vs baseline: 1.6716x; 1.6716x over previous
//
#include <hip/hip_runtime.h>
#include <hip/hip_bf16.h>

typedef __attribute__((ext_vector_type(8))) short short8;
typedef __attribute__((ext_vector_type(4))) float f32x4;

#define DEVI __device__ __forceinline__

DEVI unsigned short f2bf(float f) {
    union { float f; unsigned u; } v; v.f = f;
    unsigned r = v.u + 0x7FFFu + ((v.u >> 16) & 1u);   // RNE
    return (unsigned short)(r >> 16);
}

// packed f32x2 -> bf16x2 (v_cvt_pk_bf16_f32), RNE
DEVI unsigned cvtpk_bf16(float lo, float hi) {
    float2 t; t.x = lo; t.y = hi;
    __hip_bfloat162 h = __float22bfloat162_rn(t);
    union { __hip_bfloat162 h; unsigned u; } c; c.h = h;
    return c.u;
}

// direct HBM->LDS DMA, 16B per lane. lds dest = wave-uniform base + lane*16.
DEVI void gload_lds16(const void* g, void* l) {
    __builtin_amdgcn_global_load_lds(
        (const __attribute__((address_space(1))) unsigned int*)(unsigned long long)g,
        (__attribute__((address_space(3))) unsigned int*)(unsigned int)(unsigned long long)l,
        16, 0, 0);
}

// ---------------- 4-qubit circuit, one sample per thread ----------------
DEVI void run_circuit(const float lat[4], const float* __restrict__ qw, float out4[4])
{
    float cw[4], sw[4];
#pragma unroll
    for (int w = 0; w < 4; ++w) sincosf(0.5f * lat[w], &sw[w], &cw[w]);

    float sr[16], si[16];
#pragma unroll
    for (int s = 0; s < 16; ++s) {
        float mag = 1.f; int p = 0;
#pragma unroll
        for (int w = 0; w < 4; ++w) {
            int b = (s >> (3 - w)) & 1;
            mag *= b ? sw[w] : cw[w];
            p += b;
        }
        p &= 3;
        sr[s] = (p == 0) ? mag : ((p == 2) ? -mag : 0.f);
        si[s] = (p == 1) ? -mag : ((p == 3) ? mag : 0.f);
    }

#pragma unroll
    for (int L = 0; L < 3; ++L) {
#pragma unroll
        for (int q = 0; q < 4; ++q) {
            const float* gq = qw + (L * 4 + q) * 3;
            float phi = gq[0], th = gq[1], om = gq[2];
            float ct, st;
            sincosf(0.5f * th, &st, &ct);
            float ap = 0.5f * (phi + om), am = 0.5f * (phi - om);
            float cap, sap, cam, sam;
            sincosf(ap, &sap, &cap);
            sincosf(am, &sam, &cam);
            float u00r =  ct * cap, u00i = -ct * sap;
            float u01r = -st * cam, u01i = -st * sam;
            float u10r =  st * cam, u10i = -st * sam;
            float u11r =  ct * cap, u11i =  ct * sap;
            int bm = 8 >> q;
#pragma unroll
            for (int i = 0; i < 16; ++i) {
                if (i & bm) continue;
                int j = i | bm;
                float ar = sr[i], ai = si[i], br = sr[j], bi = si[j];
                sr[i] = u00r*ar - u00i*ai + u01r*br - u01i*bi;
                si[i] = u00r*ai + u00i*ar + u01r*bi + u01i*br;
                sr[j] = u10r*ar - u10i*ai + u11r*br - u11i*bi;
                si[j] = u10r*ai + u10i*ar + u11r*bi + u11i*br;
            }
        }
#pragma unroll
        for (int q = 0; q < 3; ++q) {
            int cm = 8 >> q, tm = 8 >> (q + 1);
#pragma unroll
            for (int i = 0; i < 16; ++i) {
                if ((i & cm) && !(i & tm)) {
                    int j = i | tm;
                    float tr = sr[i]; sr[i] = sr[j]; sr[j] = tr;
                    float ti = si[i]; si[i] = si[j]; si[j] = ti;
                }
            }
        }
    }
#pragma unroll
    for (int q = 0; q < 4; ++q) {
        int bm = 8 >> q;
        float e = 0.f;
#pragma unroll
        for (int i = 0; i < 16; ++i) {
            float p = sr[i]*sr[i] + si[i]*si[i];
            e += (i & bm) ? -p : p;
        }
        out4[q] = e;
    }
}

// ---------------- prep: weights -> bf16 [N][K] in ws ----------------
// ushort elem offsets: w0eT=0 (128x2048), w1eT=262144 (64x128),
// w1dT=270336 (128x64), w2dT=278528 (2048x128).
__global__ void prep_kernel(const float* __restrict__ ew0, const float* __restrict__ ew1,
                            const float* __restrict__ dw1, const float* __restrict__ dw2,
                            unsigned short* __restrict__ wsb)
{
    int i = blockIdx.x * 256 + threadIdx.x;
    if (i < 262144) {
        int n = i >> 11, k = i & 2047;
        wsb[i] = f2bf(ew0[k * 128 + n]);
    } else if (i < 270336) {
        int t = i - 262144; int n = t >> 7, k = t & 127;
        wsb[i] = f2bf(ew1[k * 64 + n]);
    } else if (i < 278528) {
        int t = i - 270336; int n = t >> 6, k = t & 63;
        wsb[i] = f2bf(dw1[k * 128 + n]);
    } else if (i < 540672) {
        int t = i - 278528; int n = t >> 7, k = t & 127;
        wsb[i] = f2bf(dw2[k * 2048 + n]);
    }
}

// ================= fully-fused kernel: x -> out, BM=32, 512 blocks =================
// (round-8 configuration: best measured, 89.1 us)
// LDS plan (81920 B, 2 blocks/CU = exactly 160 KiB):
//   GEMM1: A0@0 A1@8192 ([32][256B] swz f32, 3-bit slot swizzle) | B0@16384 B1@32768
//   tail:  W1E@0 ([64][256B]) W1D@16384 ([128][128B])
//     H1@49152 ([32][256B] bf16 swz) | H2@57344 (f32[32][65])
//     W2C@65664 W0D@66688 B0D@67712 | HD@68096 ([32][128B]) | GA@72192 ([32][256B])
//   GEMM3: W2a@0 W2b@32768 (each [128][256B] swz, 128-col chunks, dbuf)
__launch_bounds__(256, 2)
__global__ void fused_kernel(const float* __restrict__ x,
                             const unsigned short* __restrict__ w0T,
                             const float* __restrict__ b0e,
                             const unsigned short* __restrict__ w1eT,
                             const float* __restrict__ b1e,
                             const float* __restrict__ w2e,
                             const float* __restrict__ b2e,
                             const float* __restrict__ qw,
                             const float* __restrict__ w0d,
                             const float* __restrict__ b0d,
                             const unsigned short* __restrict__ w1dT,
                             const float* __restrict__ b1d,
                             const unsigned short* __restrict__ w2T,
                             const float* __restrict__ b2d,
                             float* __restrict__ out)
{
    __shared__ __align__(16) char smem[81920];
    char* const H1   = smem + 49152;
    float* const H2  = (float*)(smem + 57344);
    float* const W2C = (float*)(smem + 65664);
    float* const W0D = (float*)(smem + 66688);
    float* const B0D = (float*)(smem + 67712);
    char* const HD   = smem + 68096;
    char* const GA   = smem + 72192;
    char* const W1E  = smem;
    char* const W1D  = smem + 16384;

    const int tid = threadIdx.x;
    const int lane = tid & 63;
    const int wv = tid >> 6;
    const int wm = wv >> 1, wn = wv & 1;
    const int l16 = lane & 15, lq = lane >> 4;
    const int m0 = blockIdx.x * 32;

    // ======== phase 1: GEMM1  h1 = relu(x @ enc_w0 + b0e) ========
    {
        // A source: 3-bit slot swizzle (conflict-free b128 reads)
        const int rA0 = wv * 8 + (lane >> 4);
        const int rA1 = rA0 + 4;
        const char* sA0 = (const char*)(x + (long)(m0 + rA0) * 2048 + ((lane & 15) ^ (rA0 & 7)) * 4);
        const char* sA1 = (const char*)(x + (long)(m0 + rA1) * 2048 + ((lane & 15) ^ (rA1 & 7)) * 4);
        const int rB0 = wv * 32 +  0 + (lane >> 3);
        const int rB1 = wv * 32 +  8 + (lane >> 3);
        const int rB2 = wv * 32 + 16 + (lane >> 3);
        const int rB3 = wv * 32 + 24 + (lane >> 3);
        const char* sB0 = (const char*)(w0T + rB0 * 2048 + ((lane & 7) ^ (rB0 & 7)) * 8);
        const char* sB1 = (const char*)(w0T + rB1 * 2048 + ((lane & 7) ^ (rB1 & 7)) * 8);
        const char* sB2 = (const char*)(w0T + rB2 * 2048 + ((lane & 7) ^ (rB2 & 7)) * 8);
        const char* sB3 = (const char*)(w0T + rB3 * 2048 + ((lane & 7) ^ (rB3 & 7)) * 8);
        const int aoff0 = wv * 2048;
        const int aoff1 = wv * 2048 + 1024;
        const int boff0 = wv * 4096;
        const int boff1 = wv * 4096 + 1024;
        const int boff2 = wv * 4096 + 2048;
        const int boff3 = wv * 4096 + 3072;

        auto issue = [&](int cur) {
            char* Ab = smem + (cur ? 8192 : 0);
            char* Bb = smem + (cur ? 32768 : 16384);
            gload_lds16(sA0, Ab + aoff0); sA0 += 256;
            gload_lds16(sA1, Ab + aoff1); sA1 += 256;
            gload_lds16(sB0, Bb + boff0); sB0 += 128;
            gload_lds16(sB1, Bb + boff1); sB1 += 128;
            gload_lds16(sB2, Bb + boff2); sB2 += 128;
            gload_lds16(sB3, Bb + boff3); sB3 += 128;
        };

        f32x4 acc[4];
#pragma unroll
        for (int b = 0; b < 4; ++b) acc[b] = (f32x4)(0.f);

        const int arow = wm * 16 + l16;
        const int ah = arow & 7;

        issue(0);
        __syncthreads();

        for (int t = 0; t < 32; ++t) {
            if (t < 31) issue((t + 1) & 1);
            const char* Ab = smem + ((t & 1) ? 8192 : 0);
            const char* Bb = smem + ((t & 1) ? 32768 : 16384);
            const char* abase = Ab + arow * 256;
#pragma unroll
            for (int kk = 0; kk < 2; ++kk) {
                const int c = kk * 8 + lq * 2;
                float4 f0 = *(const float4*)(abase + ((c ^ ah) << 4));
                float4 f1 = *(const float4*)(abase + (((c + 1) ^ ah) << 4));
                union { unsigned u[4]; short8 s; } pk;
                pk.u[0] = cvtpk_bf16(f0.x, f0.y);
                pk.u[1] = cvtpk_bf16(f0.z, f0.w);
                pk.u[2] = cvtpk_bf16(f1.x, f1.y);
                pk.u[3] = cvtpk_bf16(f1.z, f1.w);
                short8 aF = pk.s;
#pragma unroll
                for (int fn = 0; fn < 4; ++fn) {
                    int n = wn * 64 + fn * 16 + l16;
                    short8 bF = *(const short8*)(Bb + n * 128 + (((kk * 4 + lq) ^ (n & 7)) << 4));
                    acc[fn] = __builtin_amdgcn_mfma_f32_16x16x32_bf16(aF, bF, acc[fn], 0, 0, 0);
                }
            }
            __syncthreads();
        }

        // ---- tail weight staging (into dead GEMM1 regions) + epilogue1 -> H1 ----
        {
            const int r16 = wv * 16 + (lane >> 4);
            const int s16 = lane & 15;
            const int r8  = wv * 32 + (lane >> 3);
            const int s8  = lane & 7;
#pragma unroll
            for (int i = 0; i < 4; ++i) {
                int row = r16 + i * 4;
                gload_lds16(w1eT + row * 128 + ((s16 ^ (row & 7)) * 8),
                            W1E + wv * 4096 + i * 1024);
            }
#pragma unroll
            for (int i = 0; i < 4; ++i) {
                int row = r8 + i * 8;
                gload_lds16(w1dT + row * 64 + ((s8 ^ (row & 7)) * 8),
                            W1D + wv * 4096 + i * 1024);
            }
        }
        W2C[tid] = w2e[(tid >> 2) * 32 + (tid & 3)];
        W0D[tid] = w0d[tid];
        if (tid < 64) B0D[tid] = b0d[tid];

        float b0v[4];
#pragma unroll
        for (int fn = 0; fn < 4; ++fn) b0v[fn] = b0e[wn * 64 + fn * 16 + l16];
#pragma unroll
        for (int fn = 0; fn < 4; ++fn)
#pragma unroll
            for (int r = 0; r < 4; ++r) {
                int row = wm * 16 + lq * 4 + r;
                int col = wn * 64 + fn * 16 + l16;
                float v = fmaxf(acc[fn][r] + b0v[fn], 0.f);
                *(unsigned short*)(H1 + row * 256 + ((((col >> 3) ^ (row & 7)) << 4) | ((col & 7) << 1))) = f2bf(v);
            }
    }
    __syncthreads();

    // ======== phase 2: GEMM2e  h2 = relu(h1 @ enc_w1 + b1e), 32x64, K=128 ========
    {
        f32x4 acc2[2];
#pragma unroll
        for (int b = 0; b < 2; ++b) acc2[b] = (f32x4)(0.f);
#pragma unroll
        for (int kk = 0; kk < 4; ++kk) {
            int row = wm * 16 + l16;
            short8 aF = *(const short8*)(H1 + row * 256 + (((kk * 4 + lq) ^ (row & 7)) << 4));
#pragma unroll
            for (int fn = 0; fn < 2; ++fn) {
                int n = wn * 32 + fn * 16 + l16;
                short8 bF = *(const short8*)(W1E + n * 256 + (((kk * 4 + lq) ^ (n & 7)) << 4));
                acc2[fn] = __builtin_amdgcn_mfma_f32_16x16x32_bf16(aF, bF, acc2[fn], 0, 0, 0);
            }
        }
        float b1v[2];
#pragma unroll
        for (int fn = 0; fn < 2; ++fn) b1v[fn] = b1e[wn * 32 + fn * 16 + l16];
#pragma unroll
        for (int fn = 0; fn < 2; ++fn)
#pragma unroll
            for (int r = 0; r < 4; ++r) {
                int row = wm * 16 + lq * 4 + r;
                int col = wn * 32 + fn * 16 + l16;
                H2[row * 65 + col] = fmaxf(acc2[fn][r] + b1v[fn], 0.f);
            }
    }
    __syncthreads();

    // ======== phase 3: latent + circuit + dec layer0 (one row per thread) ========
    if (tid < 32) {
        float lat[4];
#pragma unroll
        for (int j = 0; j < 4; ++j) lat[j] = b2e[j];
        const float* h2row = H2 + tid * 65;
#pragma unroll 8
        for (int k = 0; k < 64; ++k) {
            float hv = h2row[k];
#pragma unroll
            for (int j = 0; j < 4; ++j) lat[j] = fmaf(hv, W2C[k * 4 + j], lat[j]);
        }
        float o4[4];
        run_circuit(lat, qw, o4);
#pragma unroll
        for (int s = 0; s < 8; ++s) {
            uint4 pk;
            unsigned tmp[4];
#pragma unroll
            for (int p = 0; p < 4; ++p) {
                int c0 = s * 8 + p * 2;
                float v0 = fmaxf(o4[0]*W0D[c0]     + o4[1]*W0D[64+c0]   + o4[2]*W0D[128+c0]   + o4[3]*W0D[192+c0]   + B0D[c0],   0.f);
                float v1 = fmaxf(o4[0]*W0D[c0+1]   + o4[1]*W0D[64+c0+1] + o4[2]*W0D[128+c0+1] + o4[3]*W0D[192+c0+1] + B0D[c0+1], 0.f);
                tmp[p] = (unsigned)f2bf(v0) | ((unsigned)f2bf(v1) << 16);
            }
            pk.x = tmp[0]; pk.y = tmp[1]; pk.z = tmp[2]; pk.w = tmp[3];
            *(uint4*)(HD + tid * 128 + ((s ^ (tid & 7)) << 4)) = pk;
        }
    }
    __syncthreads();

    // ======== phase 4: GEMM2d  g = relu(hdec @ dec_w1 + b1d), 32x128, K=64 ========
    {
        f32x4 accg[4];
#pragma unroll
        for (int b = 0; b < 4; ++b) accg[b] = (f32x4)(0.f);
#pragma unroll
        for (int kk = 0; kk < 2; ++kk) {
            int row = wm * 16 + l16;
            short8 aF = *(const short8*)(HD + row * 128 + (((kk * 4 + lq) ^ (row & 7)) << 4));
#pragma unroll
            for (int fn = 0; fn < 4; ++fn) {
                int n = wn * 64 + fn * 16 + l16;
                short8 bF = *(const short8*)(W1D + n * 128 + (((kk * 4 + lq) ^ (n & 7)) << 4));
                accg[fn] = __builtin_amdgcn_mfma_f32_16x16x32_bf16(aF, bF, accg[fn], 0, 0, 0);
            }
        }
        float b1v[4];
#pragma unroll
        for (int fn = 0; fn < 4; ++fn) b1v[fn] = b1d[wn * 64 + fn * 16 + l16];
#pragma unroll
        for (int fn = 0; fn < 4; ++fn)
#pragma unroll
            for (int r = 0; r < 4; ++r) {
                int row = wm * 16 + lq * 4 + r;
                int col = wn * 64 + fn * 16 + l16;
                float v = fmaxf(accg[fn][r] + b1v[fn], 0.f);
                *(unsigned short*)(GA + row * 256 + ((((col >> 3) ^ (row & 7)) << 4) | ((col & 7) << 1))) = f2bf(v);
            }
    }
    __syncthreads();

    // ======== phase 5: GEMM3  out = g @ dec_w2 + b2d, 32x2048, K=128 ========
    // 16 chunks of 128 cols, double-buffered W2 (32K each) over dead W1E/W1D/H1/H2.
    {
        auto w2issue = [&](int c) {
            char* W = smem + ((c & 1) ? 32768 : 0);
            int base = c * 128;
#pragma unroll
            for (int i = 0; i < 8; ++i) {
                int row = wv * 32 + i * 4 + (lane >> 4);
                gload_lds16(w2T + (base + row) * 128 + (((lane & 15) ^ (row & 7)) * 8),
                            W + wv * 8192 + i * 1024);
            }
        };
        w2issue(0);
        __syncthreads();

        const int arow = wm * 16 + l16;
        for (int c = 0; c < 16; ++c) {
            if (c < 15) w2issue(c + 1);
            const char* W = smem + ((c & 1) ? 32768 : 0);
            f32x4 a3[4];
#pragma unroll
            for (int b = 0; b < 4; ++b) a3[b] = (f32x4)(0.f);
#pragma unroll
            for (int kk = 0; kk < 4; ++kk) {
                short8 aF = *(const short8*)(GA + arow * 256 + (((kk * 4 + lq) ^ (arow & 7)) << 4));
#pragma unroll
                for (int fn = 0; fn < 4; ++fn) {
                    int n = wn * 64 + fn * 16 + l16;
                    short8 bF = *(const short8*)(W + n * 256 + (((kk * 4 + lq) ^ (n & 7)) << 4));
                    a3[fn] = __builtin_amdgcn_mfma_f32_16x16x32_bf16(aF, bF, a3[fn], 0, 0, 0);
                }
            }
            int n0 = c * 128;
            float b2v[4];
#pragma unroll
            for (int fn = 0; fn < 4; ++fn) b2v[fn] = b2d[n0 + wn * 64 + fn * 16 + l16];
#pragma unroll
            for (int fn = 0; fn < 4; ++fn)
#pragma unroll
                for (int r = 0; r < 4; ++r) {
                    int row = m0 + wm * 16 + lq * 4 + r;
                    int col = n0 + wn * 64 + fn * 16 + l16;
                    out[(long)row * 2048 + col] = a3[fn][r] + b2v[fn];
                }
            __syncthreads();
        }
    }
}

extern "C" void kernel_launch(void* const* d_in, const int* in_sizes, int n_in,
                              void* d_out, int out_size, void* d_ws, size_t ws_size,
                              hipStream_t stream)
{
    (void)in_sizes; (void)n_in; (void)out_size; (void)ws_size;
    const float* x      = (const float*)d_in[0];
    const float* enc_w0 = (const float*)d_in[1];
    const float* enc_b0 = (const float*)d_in[2];
    const float* enc_w1 = (const float*)d_in[3];
    const float* enc_b1 = (const float*)d_in[4];
    const float* enc_w2 = (const float*)d_in[5];
    const float* enc_b2 = (const float*)d_in[6];
    const float* qw     = (const float*)d_in[7];
    const float* dec_w0 = (const float*)d_in[8];
    const float* dec_b0 = (const float*)d_in[9];
    const float* dec_w1 = (const float*)d_in[10];
    const float* dec_b1 = (const float*)d_in[11];
    const float* dec_w2 = (const float*)d_in[12];
    const float* dec_b2 = (const float*)d_in[13];

    unsigned short* wsb = (unsigned short*)d_ws;

    prep_kernel<<<2112, 256, 0, stream>>>(enc_w0, enc_w1, dec_w1, dec_w2, wsb);
    fused_kernel<<<512, 256, 0, stream>>>(x, wsb, enc_b0,
                                          wsb + 262144, enc_b1, enc_w2, enc_b2, qw,
                                          dec_w0, dec_b0, wsb + 270336, dec_b1,
                                          wsb + 278528, dec_b2, (float*)d_out);
}